// Round 1
// baseline (580.697 us; speedup 1.0000x reference)
//
#include <hip/hip_runtime.h>

#define D 128

// ---------------- CSR build ----------------

__global__ void k_count(const int* __restrict__ dst, int E, int* __restrict__ cnt) {
    int e = blockIdx.x * blockDim.x + threadIdx.x;
    if (e < E) atomicAdd(&cnt[dst[e]], 1);
}

// single-block exclusive scan of cnt[0..n) -> row_ptr, also copy to cursor; row_ptr[n]=total
__global__ void k_scan(const int* __restrict__ cnt, int* __restrict__ row_ptr,
                       int* __restrict__ cursor, int n) {
    __shared__ int wsum[16];
    __shared__ int carry_s;
    int t = threadIdx.x;
    int lane = t & 63, wid = t >> 6;
    if (t == 0) carry_s = 0;
    __syncthreads();
    for (int base = 0; base < n; base += 1024) {
        int i = base + t;
        int x = (i < n) ? cnt[i] : 0;
        int v = x;
        #pragma unroll
        for (int off = 1; off < 64; off <<= 1) {
            int y = __shfl_up(v, off, 64);
            if (lane >= off) v += y;
        }
        if (lane == 63) wsum[wid] = v;
        __syncthreads();
        if (wid == 0 && lane < 16) {
            int s = wsum[lane];
            #pragma unroll
            for (int off = 1; off < 16; off <<= 1) {
                int y = __shfl_up(s, off, 64);
                if (lane >= off) s += y;
            }
            wsum[lane] = s;
        }
        __syncthreads();
        int waveoff = (wid == 0) ? 0 : wsum[wid - 1];
        int carry = carry_s;
        int excl = carry + waveoff + v - x;
        if (i < n) { row_ptr[i] = excl; cursor[i] = excl; }
        __syncthreads();
        if (t == 1023) carry_s = carry + wsum[15];
        __syncthreads();
    }
    if (t == 0) row_ptr[n] = carry_s;
}

__global__ void k_fill(const int* __restrict__ src, const int* __restrict__ dst, int E,
                       int* __restrict__ cursor, int* __restrict__ esrc) {
    int e = blockIdx.x * blockDim.x + threadIdx.x;
    if (e < E) {
        int p = atomicAdd(&cursor[dst[e]], 1);
        esrc[p] = src[e];
    }
}

__global__ void k_dinv(const int* __restrict__ cnt, float* __restrict__ dinv, int n) {
    int v = blockIdx.x * blockDim.x + threadIdx.x;
    if (v < n) dinv[v] = rsqrtf((float)(cnt[v] + 1));  // +1 self loop
}

// ---------------- GEMM: out[r] = (X[r] @ W) * scale[r] ----------------
// block 256 threads, 32 rows/block, K chunked by 32

__global__ __launch_bounds__(256) void k_gemm_scale(
    const float* __restrict__ X, const float* __restrict__ W,
    const float* __restrict__ scale, float* __restrict__ out, int n) {
    __shared__ float Wl[32 * 128];   // K-chunk of W, row-major [k][c]
    __shared__ float xl[32 * 33];    // 32 rows x 32 k, +1 pad
    int t = threadIdx.x;
    int row0 = blockIdx.x * 32;
    int cg = t & 31;   // float4 col group -> cols cg*4..cg*4+3
    int rg = t >> 5;   // 0..7 -> rows rg*4..rg*4+3
    float acc[4][4] = {};
    for (int kk = 0; kk < 4; kk++) {
        const float4* Wg4 = (const float4*)(W + kk * 32 * 128);
        float4* Wl4 = (float4*)Wl;
        Wl4[t]       = Wg4[t];
        Wl4[t + 256] = Wg4[t + 256];
        Wl4[t + 512] = Wg4[t + 512];
        Wl4[t + 768] = Wg4[t + 768];
        {
            int r = t >> 3, k4 = t & 7;
            int row = row0 + r;
            float4 v = make_float4(0.f, 0.f, 0.f, 0.f);
            if (row < n) v = *(const float4*)&X[(size_t)row * D + kk * 32 + k4 * 4];
            xl[r * 33 + k4 * 4 + 0] = v.x;
            xl[r * 33 + k4 * 4 + 1] = v.y;
            xl[r * 33 + k4 * 4 + 2] = v.z;
            xl[r * 33 + k4 * 4 + 3] = v.w;
        }
        __syncthreads();
        const float4* Wc = (const float4*)Wl;
        #pragma unroll 8
        for (int k = 0; k < 32; k++) {
            float4 w = Wc[k * 32 + cg];
            #pragma unroll
            for (int i = 0; i < 4; i++) {
                float xv = xl[(rg * 4 + i) * 33 + k];
                acc[i][0] += xv * w.x;
                acc[i][1] += xv * w.y;
                acc[i][2] += xv * w.z;
                acc[i][3] += xv * w.w;
            }
        }
        __syncthreads();
    }
    #pragma unroll
    for (int i = 0; i < 4; i++) {
        int row = row0 + rg * 4 + i;
        if (row < n) {
            float s = scale[row];
            float4 o = make_float4(acc[i][0] * s, acc[i][1] * s, acc[i][2] * s, acc[i][3] * s);
            *(float4*)&out[(size_t)row * D + cg * 4] = o;
        }
    }
}

// ---------------- Aggregation: Y[v] = dinv[v]*(sum_{u in in(v)} hs[u] + hs[v]) + b ----
// one wave (64 lanes) per node, float2/lane = full 512B row

__global__ __launch_bounds__(256) void k_agg(
    const float* __restrict__ hs, const int* __restrict__ row_ptr,
    const int* __restrict__ esrc, const float* __restrict__ dinv,
    const float* __restrict__ bias, float* __restrict__ out, int n) {
    int node = blockIdx.x * 4 + (threadIdx.x >> 6);
    if (node >= n) return;
    int lane = threadIdx.x & 63;
    int beg = row_ptr[node], end = row_ptr[node + 1];
    // self loop
    float2 acc = *(const float2*)&hs[(size_t)node * D + lane * 2];
    for (int base = beg; base < end; base += 64) {
        int m = end - base;
        if (m > 64) m = 64;
        int eid = (base + lane < end) ? esrc[base + lane] : 0;
        int i = 0;
        for (; i + 4 <= m; i += 4) {
            int u0 = __shfl(eid, i, 64);
            int u1 = __shfl(eid, i + 1, 64);
            int u2 = __shfl(eid, i + 2, 64);
            int u3 = __shfl(eid, i + 3, 64);
            float2 v0 = *(const float2*)&hs[(size_t)u0 * D + lane * 2];
            float2 v1 = *(const float2*)&hs[(size_t)u1 * D + lane * 2];
            float2 v2 = *(const float2*)&hs[(size_t)u2 * D + lane * 2];
            float2 v3 = *(const float2*)&hs[(size_t)u3 * D + lane * 2];
            acc.x += v0.x + v1.x + v2.x + v3.x;
            acc.y += v0.y + v1.y + v2.y + v3.y;
        }
        for (; i < m; i++) {
            int u = __shfl(eid, i, 64);
            float2 v = *(const float2*)&hs[(size_t)u * D + lane * 2];
            acc.x += v.x;
            acc.y += v.y;
        }
    }
    float s = dinv[node];
    float2 b = *(const float2*)&bias[lane * 2];
    float2 r;
    r.x = acc.x * s + b.x;
    r.y = acc.y * s + b.y;
    *(float2*)&out[(size_t)node * D + lane * 2] = r;
}

// ---------------- BatchNorm ----------------

__global__ __launch_bounds__(256) void k_bn_stats(const float* __restrict__ y,
                                                  float* __restrict__ stats, int n) {
    // stats[0..127]=sum, stats[128..255]=sumsq (pre-zeroed)
    int c = threadIdx.x & 127;
    int half = threadIdx.x >> 7;
    float s = 0.f, q = 0.f;
    for (int r = blockIdx.x * 2 + half; r < n; r += gridDim.x * 2) {
        float v = y[(size_t)r * D + c];
        s += v;
        q += v * v;
    }
    __shared__ float ls[256], lq[256];
    ls[threadIdx.x] = s;
    lq[threadIdx.x] = q;
    __syncthreads();
    if (half == 0) {
        s = ls[threadIdx.x] + ls[threadIdx.x + 128];
        q = lq[threadIdx.x] + lq[threadIdx.x + 128];
        atomicAdd(&stats[c], s);
        atomicAdd(&stats[128 + c], q);
    }
}

__global__ void k_bn_finalize(float* __restrict__ stats, const float* __restrict__ gamma,
                              const float* __restrict__ beta, float n) {
    int c = threadIdx.x;  // 128 threads
    float mean = stats[c] / n;
    float var = stats[128 + c] / n - mean * mean;
    float a = gamma[c] * rsqrtf(var + 1e-5f);
    float b = beta[c] - mean * a;
    stats[c] = a;
    stats[128 + c] = b;
}

__global__ __launch_bounds__(256) void k_bn_relu(float* __restrict__ y,
                                                 const float* __restrict__ stats, int n) {
    int idx = blockIdx.x * 256 + threadIdx.x;  // over n*32 float4s
    if (idx >= n * 32) return;
    int c4 = idx & 31;
    float4 v = ((const float4*)y)[idx];
    float4 o;
    o.x = fmaxf(v.x * stats[c4 * 4 + 0] + stats[128 + c4 * 4 + 0], 0.f);
    o.y = fmaxf(v.y * stats[c4 * 4 + 1] + stats[128 + c4 * 4 + 1], 0.f);
    o.z = fmaxf(v.z * stats[c4 * 4 + 2] + stats[128 + c4 * 4 + 2], 0.f);
    o.w = fmaxf(v.w * stats[c4 * 4 + 3] + stats[128 + c4 * 4 + 3], 0.f);
    ((float4*)y)[idx] = o;
}

// ---------------- row L2 normalize ----------------

__global__ __launch_bounds__(256) void k_l2norm(const float* __restrict__ h,
                                                float* __restrict__ out, int n) {
    int node = blockIdx.x * 4 + (threadIdx.x >> 6);
    if (node >= n) return;
    int lane = threadIdx.x & 63;
    float2 v = *(const float2*)&h[(size_t)node * D + lane * 2];
    float p = v.x * v.x + v.y * v.y;
    #pragma unroll
    for (int off = 32; off > 0; off >>= 1) p += __shfl_xor(p, off, 64);
    float sc = 1.0f / fmaxf(sqrtf(p), 1e-12f);
    float2 r;
    r.x = v.x * sc;
    r.y = v.y * sc;
    *(float2*)&out[(size_t)node * D + lane * 2] = r;
}

// ---------------- launch ----------------

extern "C" void kernel_launch(void* const* d_in, const int* in_sizes, int n_in,
                              void* d_out, int out_size, void* d_ws, size_t ws_size,
                              hipStream_t stream) {
    const float* x  = (const float*)d_in[0];
    const int*   ei = (const int*)d_in[1];
    const float* W1 = (const float*)d_in[2];
    const float* b1 = (const float*)d_in[3];
    const float* W2 = (const float*)d_in[4];
    const float* b2 = (const float*)d_in[5];
    const float* W3 = (const float*)d_in[6];
    const float* b3 = (const float*)d_in[7];
    const float* g1 = (const float*)d_in[8];
    const float* be1 = (const float*)d_in[9];
    const float* g2 = (const float*)d_in[10];
    const float* be2 = (const float*)d_in[11];

    const int N = in_sizes[0] / D;
    const int E = in_sizes[1] / 2;
    const int* src = ei;
    const int* dst = ei + E;

    // workspace carve
    float* hsA     = (float*)d_ws;          // N*D
    float* hsB     = hsA + (size_t)N * D;   // N*D
    float* dinv    = hsB + (size_t)N * D;   // N
    float* stats   = dinv + N;              // 256
    int*   cnt     = (int*)(stats + 256);   // N
    int*   row_ptr = cnt + N;               // N+1
    int*   cursor  = row_ptr + N + 1;       // N
    int*   esrc    = cursor + N;            // E

    const int TB = 256;
    const int gE = (E + TB - 1) / TB;
    const int gN = (N + TB - 1) / TB;
    const int gRows = (N + 31) / 32;
    const int gNode = (N + 3) / 4;
    const int gElem4 = (N * 32 + TB - 1) / TB;

    // CSR build
    hipMemsetAsync(cnt, 0, (size_t)N * sizeof(int), stream);
    k_count<<<gE, TB, 0, stream>>>(dst, E, cnt);
    k_scan<<<1, 1024, 0, stream>>>(cnt, row_ptr, cursor, N);
    k_dinv<<<gN, TB, 0, stream>>>(cnt, dinv, N);
    k_fill<<<gE, TB, 0, stream>>>(src, dst, E, cursor, esrc);

    // layer 1
    k_gemm_scale<<<gRows, TB, 0, stream>>>(x, W1, dinv, hsA, N);
    k_agg<<<gNode, TB, 0, stream>>>(hsA, row_ptr, esrc, dinv, b1, hsB, N);
    hipMemsetAsync(stats, 0, 256 * sizeof(float), stream);
    k_bn_stats<<<256, TB, 0, stream>>>(hsB, stats, N);
    k_bn_finalize<<<1, 128, 0, stream>>>(stats, g1, be1, (float)N);
    k_bn_relu<<<gElem4, TB, 0, stream>>>(hsB, stats, N);

    // layer 2
    k_gemm_scale<<<gRows, TB, 0, stream>>>(hsB, W2, dinv, hsA, N);
    k_agg<<<gNode, TB, 0, stream>>>(hsA, row_ptr, esrc, dinv, b2, hsB, N);
    hipMemsetAsync(stats, 0, 256 * sizeof(float), stream);
    k_bn_stats<<<256, TB, 0, stream>>>(hsB, stats, N);
    k_bn_finalize<<<1, 128, 0, stream>>>(stats, g2, be2, (float)N);
    k_bn_relu<<<gElem4, TB, 0, stream>>>(hsB, stats, N);

    // layer 3 + normalize
    k_gemm_scale<<<gRows, TB, 0, stream>>>(hsB, W3, dinv, hsA, N);
    k_agg<<<gNode, TB, 0, stream>>>(hsA, row_ptr, esrc, dinv, b3, hsB, N);
    k_l2norm<<<gNode, TB, 0, stream>>>(hsB, (float*)d_out, N);
}

// Round 2
// 485.245 us; speedup vs baseline: 1.1967x; 1.1967x over previous
//
#include <hip/hip_runtime.h>
#include <hip/hip_bf16.h>

#define D 128
#define PADR 260   // xt row pad: multiple of 4 (16B-aligned ds_read_b128), 260%32=4 staggers banks

// ---------------- CSR build ----------------

__global__ void k_count(const int* __restrict__ dst, int E, int* __restrict__ cnt) {
    int e = blockIdx.x * blockDim.x + threadIdx.x;
    if (e < E) atomicAdd(&cnt[dst[e]], 1);
}

// per-block sums of cnt
__global__ __launch_bounds__(256) void k_scan1(const int* __restrict__ cnt, int n,
                                               int* __restrict__ bsum) {
    int i = blockIdx.x * 256 + threadIdx.x;
    int x = (i < n) ? cnt[i] : 0;
    #pragma unroll
    for (int off = 32; off > 0; off >>= 1) x += __shfl_xor(x, off, 64);
    __shared__ int ws[4];
    if ((threadIdx.x & 63) == 0) ws[threadIdx.x >> 6] = x;
    __syncthreads();
    if (threadIdx.x == 0) bsum[blockIdx.x] = ws[0] + ws[1] + ws[2] + ws[3];
}

// exclusive scan of block sums (nb <= 256), single block of 256
__global__ void k_scan2(const int* __restrict__ bsum, int nb, int* __restrict__ boff) {
    int t = threadIdx.x;
    int lane = t & 63, wid = t >> 6;
    int x = (t < nb) ? bsum[t] : 0;
    int incl = x;
    #pragma unroll
    for (int off = 1; off < 64; off <<= 1) {
        int y = __shfl_up(incl, off, 64);
        if (lane >= off) incl += y;
    }
    __shared__ int ws[4];
    if (lane == 63) ws[wid] = incl;
    __syncthreads();
    int o = 0;
    for (int w = 0; w < wid; w++) o += ws[w];
    if (t < nb) boff[t] = o + incl - x;
}

// final: row_ptr/cursor/dinv
__global__ __launch_bounds__(256) void k_scan3(const int* __restrict__ cnt,
                                               const int* __restrict__ boff, int n, int E,
                                               int* __restrict__ row_ptr, int* __restrict__ cursor,
                                               float* __restrict__ dinv) {
    int t = threadIdx.x;
    int lane = t & 63, wid = t >> 6;
    int i = blockIdx.x * 256 + t;
    int x = (i < n) ? cnt[i] : 0;
    int incl = x;
    #pragma unroll
    for (int off = 1; off < 64; off <<= 1) {
        int y = __shfl_up(incl, off, 64);
        if (lane >= off) incl += y;
    }
    __shared__ int ws[4];
    if (lane == 63) ws[wid] = incl;
    __syncthreads();
    int o = boff[blockIdx.x];
    for (int w = 0; w < wid; w++) o += ws[w];
    if (i < n) {
        int excl = o + incl - x;
        row_ptr[i] = excl;
        cursor[i] = excl;
        dinv[i] = rsqrtf((float)(x + 1));  // +1 self loop
    }
    if (blockIdx.x == 0 && t == 0) row_ptr[n] = E;
}

__global__ void k_fill(const int* __restrict__ src, const int* __restrict__ dst, int E,
                       int* __restrict__ cursor, int* __restrict__ esrc) {
    int e = blockIdx.x * blockDim.x + threadIdx.x;
    if (e < E) {
        int p = atomicAdd(&cursor[dst[e]], 1);
        esrc[p] = src[e];
    }
}

// ---------------- GEMM: hs[r] = bf16( relu_bn(X[r]) @ W * dinv[r] ) ----------------
// 256 threads, 256 rows/block, per-thread 16 rows x 8 cols, K chunks of 32.
// X chunk stored TRANSPOSED in LDS -> inner loop is 6x ds_read_b128 per k.
// bn != nullptr: apply y = max(a*x+b, 0) on load (a=bn[c], b=bn[128+c]).

__global__ __launch_bounds__(256, 1) void k_gemm(
    const float* __restrict__ X, const float* __restrict__ W,
    const float* __restrict__ scale, const float* __restrict__ bn,
    unsigned short* __restrict__ hs, int n) {
    __shared__ float xt[32 * PADR];   // [k][r] transposed
    __shared__ float Wl[32 * 128];    // [k][c]
    int t = threadIdx.x;
    int row0 = blockIdx.x * 256;
    int cg = t & 15, rg = t >> 4;
    int c0 = cg * 8, r0 = rg * 16;
    float acc[16][8];
    #pragma unroll
    for (int i = 0; i < 16; i++)
        #pragma unroll
        for (int j = 0; j < 8; j++) acc[i][j] = 0.f;

    for (int kk = 0; kk < 4; kk++) {
        // stage W chunk (row-major, b128 all the way)
        const float4* Wg4 = (const float4*)(W + kk * 32 * 128);
        float4* Wl4 = (float4*)Wl;
        #pragma unroll
        for (int j = 0; j < 4; j++) Wl4[t + j * 256] = Wg4[t + j * 256];
        // stage X chunk transposed
        int rl = t >> 3, k4 = t & 7;
        #pragma unroll
        for (int j = 0; j < 8; j++) {
            int r = rl + j * 32;
            int row = row0 + r;
            float4 v = make_float4(0.f, 0.f, 0.f, 0.f);
            if (row < n) {
                v = *(const float4*)&X[(size_t)row * D + kk * 32 + k4 * 4];
                if (bn) {
                    int c = kk * 32 + k4 * 4;
                    v.x = fmaxf(v.x * bn[c + 0] + bn[128 + c + 0], 0.f);
                    v.y = fmaxf(v.y * bn[c + 1] + bn[128 + c + 1], 0.f);
                    v.z = fmaxf(v.z * bn[c + 2] + bn[128 + c + 2], 0.f);
                    v.w = fmaxf(v.w * bn[c + 3] + bn[128 + c + 3], 0.f);
                }
            }
            xt[(k4 * 4 + 0) * PADR + r] = v.x;
            xt[(k4 * 4 + 1) * PADR + r] = v.y;
            xt[(k4 * 4 + 2) * PADR + r] = v.z;
            xt[(k4 * 4 + 3) * PADR + r] = v.w;
        }
        __syncthreads();
        for (int k = 0; k < 32; k++) {
            float4 x0 = *(const float4*)&xt[k * PADR + r0];
            float4 x1 = *(const float4*)&xt[k * PADR + r0 + 4];
            float4 x2 = *(const float4*)&xt[k * PADR + r0 + 8];
            float4 x3 = *(const float4*)&xt[k * PADR + r0 + 12];
            float4 w0 = *(const float4*)&Wl[k * 128 + c0];
            float4 w1 = *(const float4*)&Wl[k * 128 + c0 + 4];
            float xr[16] = {x0.x, x0.y, x0.z, x0.w, x1.x, x1.y, x1.z, x1.w,
                            x2.x, x2.y, x2.z, x2.w, x3.x, x3.y, x3.z, x3.w};
            float wc[8] = {w0.x, w0.y, w0.z, w0.w, w1.x, w1.y, w1.z, w1.w};
            #pragma unroll
            for (int i = 0; i < 16; i++)
                #pragma unroll
                for (int j = 0; j < 8; j++) acc[i][j] += xr[i] * wc[j];
        }
        __syncthreads();
    }
    // epilogue: *dinv, pack bf16, one dwordx4 store per row
    #pragma unroll
    for (int i = 0; i < 16; i++) {
        int row = row0 + r0 + i;
        if (row < n) {
            float s = scale[row];
            unsigned u[4];
            #pragma unroll
            for (int jj = 0; jj < 4; jj++) {
                __hip_bfloat16 lo = __float2bfloat16(acc[i][2 * jj] * s);
                __hip_bfloat16 hi = __float2bfloat16(acc[i][2 * jj + 1] * s);
                u[jj] = (unsigned)*(unsigned short*)&lo |
                        ((unsigned)*(unsigned short*)&hi << 16);
            }
            *(uint4*)&hs[(size_t)row * D + c0] = *(uint4*)u;
        }
    }
}

// ---------------- Aggregation over bf16 hs ----------------
// Y[v] = dinv[v]*(sum_{u in in(v)} hs[u] + hs[v]) + b ; optional row L2-normalize.
// one wave per node; lane holds one packed bf16x2 (4B) => 256B row per wave.

__device__ inline float2 bf2f(unsigned u) {
    union { unsigned i; float f; } lo, hi;
    lo.i = u << 16;
    hi.i = u & 0xffff0000u;
    float2 r; r.x = lo.f; r.y = hi.f; return r;
}

__global__ __launch_bounds__(256) void k_agg(
    const unsigned* __restrict__ hs, const int* __restrict__ row_ptr,
    const int* __restrict__ esrc, const float* __restrict__ dinv,
    const float* __restrict__ bias, float* __restrict__ out, int n, int do_norm) {
    int node = blockIdx.x * 4 + (threadIdx.x >> 6);
    if (node >= n) return;
    int lane = threadIdx.x & 63;
    int beg = row_ptr[node], end = row_ptr[node + 1];
    // self loop
    float2 acc = bf2f(hs[(size_t)node * 64 + lane]);
    for (int base = beg; base < end; base += 64) {
        int m = end - base;
        if (m > 64) m = 64;
        int eid = (base + lane < end) ? esrc[base + lane] : 0;
        int i = 0;
        for (; i + 4 <= m; i += 4) {
            int u0 = __shfl(eid, i, 64);
            int u1 = __shfl(eid, i + 1, 64);
            int u2 = __shfl(eid, i + 2, 64);
            int u3 = __shfl(eid, i + 3, 64);
            unsigned p0 = hs[(size_t)u0 * 64 + lane];
            unsigned p1 = hs[(size_t)u1 * 64 + lane];
            unsigned p2 = hs[(size_t)u2 * 64 + lane];
            unsigned p3 = hs[(size_t)u3 * 64 + lane];
            float2 v0 = bf2f(p0), v1 = bf2f(p1), v2 = bf2f(p2), v3 = bf2f(p3);
            acc.x += (v0.x + v1.x) + (v2.x + v3.x);
            acc.y += (v0.y + v1.y) + (v2.y + v3.y);
        }
        for (; i < m; i++) {
            int u = __shfl(eid, i, 64);
            float2 v = bf2f(hs[(size_t)u * 64 + lane]);
            acc.x += v.x;
            acc.y += v.y;
        }
    }
    float s = dinv[node];
    float2 b = *(const float2*)&bias[lane * 2];
    float2 r;
    r.x = acc.x * s + b.x;
    r.y = acc.y * s + b.y;
    if (do_norm) {
        float p = r.x * r.x + r.y * r.y;
        #pragma unroll
        for (int off = 32; off > 0; off >>= 1) p += __shfl_xor(p, off, 64);
        float sc = 1.0f / fmaxf(sqrtf(p), 1e-12f);
        r.x *= sc;
        r.y *= sc;
    }
    *(float2*)&out[(size_t)node * D + lane * 2] = r;
}

// ---------------- BatchNorm stats ----------------

__global__ __launch_bounds__(256) void k_bn_stats(const float* __restrict__ y,
                                                  float* __restrict__ stats, int n) {
    int c = threadIdx.x & 127;
    int half = threadIdx.x >> 7;
    float s = 0.f, q = 0.f;
    for (int r = blockIdx.x * 2 + half; r < n; r += gridDim.x * 2) {
        float v = y[(size_t)r * D + c];
        s += v;
        q += v * v;
    }
    __shared__ float ls[256], lq[256];
    ls[threadIdx.x] = s;
    lq[threadIdx.x] = q;
    __syncthreads();
    if (half == 0) {
        s = ls[threadIdx.x] + ls[threadIdx.x + 128];
        q = lq[threadIdx.x] + lq[threadIdx.x + 128];
        atomicAdd(&stats[c], s);
        atomicAdd(&stats[128 + c], q);
    }
}

__global__ void k_bn_finalize(float* __restrict__ stats, const float* __restrict__ gamma,
                              const float* __restrict__ beta, float n) {
    int c = threadIdx.x;  // 128 threads
    float mean = stats[c] / n;
    float var = stats[128 + c] / n - mean * mean;
    float a = gamma[c] * rsqrtf(var + 1e-5f);
    float b = beta[c] - mean * a;
    stats[c] = a;
    stats[128 + c] = b;
}

// ---------------- launch ----------------

extern "C" void kernel_launch(void* const* d_in, const int* in_sizes, int n_in,
                              void* d_out, int out_size, void* d_ws, size_t ws_size,
                              hipStream_t stream) {
    const float* x  = (const float*)d_in[0];
    const int*   ei = (const int*)d_in[1];
    const float* W1 = (const float*)d_in[2];
    const float* b1 = (const float*)d_in[3];
    const float* W2 = (const float*)d_in[4];
    const float* b2 = (const float*)d_in[5];
    const float* W3 = (const float*)d_in[6];
    const float* b3 = (const float*)d_in[7];
    const float* g1 = (const float*)d_in[8];
    const float* be1 = (const float*)d_in[9];
    const float* g2 = (const float*)d_in[10];
    const float* be2 = (const float*)d_in[11];

    const int N = in_sizes[0] / D;
    const int E = in_sizes[1] / 2;
    const int* src = ei;
    const int* dst = ei + E;

    // workspace carve
    float* Y       = (float*)d_ws;              // N*D fp32
    unsigned short* hs = (unsigned short*)(Y + (size_t)N * D);  // N*D bf16
    float* dinv    = (float*)(hs + (size_t)N * D);  // N
    float* stats   = dinv + N;                  // 256
    int*   cnt     = (int*)(stats + 256);       // N
    int*   row_ptr = cnt + N;                   // N+1
    int*   cursor  = row_ptr + N + 1;           // N
    int*   bsum    = cursor + N;                // NB
    int*   boff    = bsum + 256;                // NB
    int*   esrc    = boff + 256;                // E

    const int TB = 256;
    const int gE = (E + TB - 1) / TB;
    const int NB = (N + 255) / 256;   // 196: scan blocks == gemm blocks
    const int gNode = (N + 3) / 4;

    // CSR build
    hipMemsetAsync(cnt, 0, (size_t)N * sizeof(int), stream);
    k_count<<<gE, TB, 0, stream>>>(dst, E, cnt);
    k_scan1<<<NB, TB, 0, stream>>>(cnt, N, bsum);
    k_scan2<<<1, 256, 0, stream>>>(bsum, NB, boff);
    k_scan3<<<NB, TB, 0, stream>>>(cnt, boff, N, E, row_ptr, cursor, dinv);
    k_fill<<<gE, TB, 0, stream>>>(src, dst, E, cursor, esrc);

    // layer 1
    k_gemm<<<NB, TB, 0, stream>>>(x, W1, dinv, nullptr, hs, N);
    k_agg<<<gNode, TB, 0, stream>>>((const unsigned*)hs, row_ptr, esrc, dinv, b1, Y, N, 0);
    hipMemsetAsync(stats, 0, 256 * sizeof(float), stream);
    k_bn_stats<<<256, TB, 0, stream>>>(Y, stats, N);
    k_bn_finalize<<<1, 128, 0, stream>>>(stats, g1, be1, (float)N);

    // layer 2 (BN+ReLU fused into gemm load)
    k_gemm<<<NB, TB, 0, stream>>>(Y, W2, dinv, stats, hs, N);
    k_agg<<<gNode, TB, 0, stream>>>((const unsigned*)hs, row_ptr, esrc, dinv, b2, Y, N, 0);
    hipMemsetAsync(stats, 0, 256 * sizeof(float), stream);
    k_bn_stats<<<256, TB, 0, stream>>>(Y, stats, N);
    k_bn_finalize<<<1, 128, 0, stream>>>(stats, g2, be2, (float)N);

    // layer 3 (+ fused L2 normalize, straight to d_out)
    k_gemm<<<NB, TB, 0, stream>>>(Y, W3, dinv, stats, hs, N);
    k_agg<<<gNode, TB, 0, stream>>>((const unsigned*)hs, row_ptr, esrc, dinv, b3,
                                    (float*)d_out, N, 1);
}